// Round 6
// baseline (1835.893 us; speedup 1.0000x reference)
//
#include <hip/hip_runtime.h>
#include <hip/hip_bf16.h>

// ---------------------------------------------------------------------------
// Fused 2-layer GRU + ReLU + Linear. One batch element per workgroup (256 WGs).
// Round-6: matvecs moved from the VALU (v_dot2 measured ~3x slower than its
// 2-cyc ideal across R1-R5) to the idle MFMA pipe. mfma_f32_16x16x32_f16 with
// the state vector broadcast to all 16 B-columns (M=1 useful row); weights
// are persistent A-fragments (f16, AGPR-native operands -> no move cost).
// Per wave: 6 row-tiles (2 rz + 1 n per layer), x/h parts in separate accs ->
// 12 independent MFMA chains of depth <=4. E-phase: gate pre-acts are single
// f32 LDS reads (no partial sums). Cross-layer 2-barrier pipeline retained:
// phase M computes L2 gates for t AND L1 gates for t+1; phase E updates both.
// ---------------------------------------------------------------------------

typedef _Float16 f16x8 __attribute__((ext_vector_type(8)));
typedef float f32x4 __attribute__((ext_vector_type(4)));

#define SEQ 1200
#define HID 128
#define INSZ 32

__device__ __forceinline__ float sigm(float x) {
  return 1.0f / (1.0f + __expf(-x));
}
__device__ __forceinline__ float tanh_f(float x) {
  x = fminf(fmaxf(x, -15.f), 15.f);
  float e = __expf(2.f * x);
  return (e - 1.f) / (e + 1.f);
}

// Load 8 consecutive f32 weights, convert to an f16x8 A-fragment.
__device__ __forceinline__ f16x8 loadA(const float* p) {
  float4 u = ((const float4*)p)[0], v = ((const float4*)p)[1];
  f16x8 r;
  r[0] = (_Float16)u.x; r[1] = (_Float16)u.y; r[2] = (_Float16)u.z; r[3] = (_Float16)u.w;
  r[4] = (_Float16)v.x; r[5] = (_Float16)v.y; r[6] = (_Float16)v.z; r[7] = (_Float16)v.w;
  return r;
}

#define MFMA(A, B, C) __builtin_amdgcn_mfma_f32_16x16x32_f16((A), (B), (C), 0, 0, 0)

__global__ __launch_bounds__(512, 1) void gru_fused(
    const float* __restrict__ x,
    const float* __restrict__ Wih0, const float* __restrict__ Whh0,
    const float* __restrict__ bih0, const float* __restrict__ bhh0,
    const float* __restrict__ Wih1, const float* __restrict__ Whh1,
    const float* __restrict__ bih1, const float* __restrict__ bhh1,
    const float* __restrict__ Wlin, const float* __restrict__ blin,
    float* __restrict__ out)
{
  const int tid  = threadIdx.x;
  const int b    = blockIdx.x;
  const int wid  = tid >> 6;    // wave 0..7
  const int lane = tid & 63;
  const int lr   = lane & 15;   // A-frag row within tile
  const int lg   = lane >> 4;   // k-group 0..3

  // gate pre-activations, x-part and h-part separate (f32, full rows)
  __shared__ float G1x[384], G1h[384];   // layer1 (for t+1)
  __shared__ float G2x[384], G2h[384];   // layer2 (for t)
  __shared__ float s0f[HID], s1f[HID];   // fp32 master states
  __shared__ __align__(16) _Float16 s0h[HID], s1h[HID];  // f16 copies (MFMA B)
  __shared__ __align__(16) _Float16 xh[2][INSZ];         // f16 x row, dbl buf
  __shared__ float pbf[32];              // output partials, double buffer

  // Row-tile bases for this wave: 2 rz tiles (rows 0..255) + 1 n tile (256..383)
  const int RZ0 = wid * 32, RZ1 = wid * 32 + 16, NR = 256 + wid * 16;

  // ---- persistent weight A-fragments (f16), 39 frags = 156 regs ----
  // A-layout (16x16x32): lane holds A[lane&15][(lane>>4)*8 + j], j=0..7
  f16x8 Ax0, Ax1, AxN;                 // Wih0 (K=32, one k-tile)
  f16x8 Ah0[3][4], Ai1[3][4], Ah1w[3][4];  // Whh0 / Wih1 / Whh1 (K=128)
  {
    const int r0 = RZ0 + lr, r1 = RZ1 + lr, rn = NR + lr;
    const int kb = lg * 8;
    Ax0 = loadA(Wih0 + (size_t)r0 * INSZ + kb);
    Ax1 = loadA(Wih0 + (size_t)r1 * INSZ + kb);
    AxN = loadA(Wih0 + (size_t)rn * INSZ + kb);
#pragma unroll
    for (int kt = 0; kt < 4; ++kt) {
      const int ko = kt * 32 + kb;
      Ah0[0][kt]  = loadA(Whh0 + (size_t)r0 * HID + ko);
      Ah0[1][kt]  = loadA(Whh0 + (size_t)r1 * HID + ko);
      Ah0[2][kt]  = loadA(Whh0 + (size_t)rn * HID + ko);
      Ai1[0][kt]  = loadA(Wih1 + (size_t)r0 * HID + ko);
      Ai1[1][kt]  = loadA(Wih1 + (size_t)r1 * HID + ko);
      Ai1[2][kt]  = loadA(Wih1 + (size_t)rn * HID + ko);
      Ah1w[0][kt] = loadA(Whh1 + (size_t)r0 * HID + ko);
      Ah1w[1][kt] = loadA(Whh1 + (size_t)r1 * HID + ko);
      Ah1w[2][kt] = loadA(Whh1 + (size_t)rn * HID + ko);
    }
  }

  // E-phase per-thread constants
  float bA = 0.f, bB = 0.f, bC = 0.f, bD = 0.f, wl = 0.f;
  if (tid < 128) {                 // L2 updater for row tid
    bA = bih1[tid] + bhh1[tid];
    bB = bih1[HID + tid] + bhh1[HID + tid];
    bC = bih1[2 * HID + tid];
    bD = bhh1[2 * HID + tid];
    wl = Wlin[tid];
  } else if (tid < 256) {          // L1 updater
    const int i = tid - 128;
    bA = bih0[i] + bhh0[i];
    bB = bih0[HID + i] + bhh0[HID + i];
    bC = bih0[2 * HID + i];
    bD = bhh0[2 * HID + i];
  }
  const float blv = blin[0];

  // ---- init: zero states, pack x_0 ----
  if (tid < HID) {
    s0f[tid] = 0.f; s1f[tid] = 0.f;
    s0h[tid] = (_Float16)0.f; s1h[tid] = (_Float16)0.f;
  }
  const float2* xsrc = (const float2*)x + (size_t)b * SEQ * (INSZ / 2);
  if (tid < 16) {
    float2 v = xsrc[tid];
    xh[0][2 * tid] = (_Float16)v.x; xh[0][2 * tid + 1] = (_Float16)v.y;
  }
  __syncthreads();

  float* outp = out + (size_t)b * SEQ;

  for (int t = -1; t < SEQ; ++t) {
    // ================= phase M: all matvecs on the MFMA pipe =================
    {
      // B-fragments: state broadcast to all 16 columns.
      // B-layout: lane holds B[(lane>>4)*8 + j][lane&15] -> read 8 contiguous
      // f16 of the k-slice (same addr for all 16 lanes of a group = broadcast).
      f16x8 Bh1[4], Bh2[4], Bx;
#pragma unroll
      for (int kt = 0; kt < 4; ++kt) {
        Bh1[kt] = *(const f16x8*)(s0h + kt * 32 + lg * 8);
        Bh2[kt] = *(const f16x8*)(s1h + kt * 32 + lg * 8);
      }
      Bx = *(const f16x8*)(xh[(t + 1) & 1] + lg * 8);

      const f32x4 Z = {0.f, 0.f, 0.f, 0.f};
      f32x4 a0x = MFMA(Ax0, Bx, Z);
      f32x4 a1x = MFMA(Ax1, Bx, Z);
      f32x4 anx = MFMA(AxN, Bx, Z);
      f32x4 a0h = Z, a1h = Z, anh = Z;
      f32x4 c0x = Z, c1x = Z, cnx = Z, c0h = Z, c1h = Z, cnh = Z;
#pragma unroll
      for (int kt = 0; kt < 4; ++kt) {
        a0h = MFMA(Ah0[0][kt],  Bh1[kt], a0h);
        a1h = MFMA(Ah0[1][kt],  Bh1[kt], a1h);
        anh = MFMA(Ah0[2][kt],  Bh1[kt], anh);
        c0x = MFMA(Ai1[0][kt],  Bh1[kt], c0x);
        c1x = MFMA(Ai1[1][kt],  Bh1[kt], c1x);
        cnx = MFMA(Ai1[2][kt],  Bh1[kt], cnx);
        c0h = MFMA(Ah1w[0][kt], Bh2[kt], c0h);
        c1h = MFMA(Ah1w[1][kt], Bh2[kt], c1h);
        cnh = MFMA(Ah1w[2][kt], Bh2[kt], cnh);
      }
      // C/D layout: col=lane&15, row=(lane>>4)*4+reg. All cols equal; col-0
      // lanes write their 4 contiguous rows as one b128.
      if (lr == 0) {
        const int ro = lg * 4;
        *(f32x4*)(G1x + RZ0 + ro) = a0x; *(f32x4*)(G1x + RZ1 + ro) = a1x;
        *(f32x4*)(G1x + NR  + ro) = anx;
        *(f32x4*)(G1h + RZ0 + ro) = a0h; *(f32x4*)(G1h + RZ1 + ro) = a1h;
        *(f32x4*)(G1h + NR  + ro) = anh;
        *(f32x4*)(G2x + RZ0 + ro) = c0x; *(f32x4*)(G2x + RZ1 + ro) = c1x;
        *(f32x4*)(G2x + NR  + ro) = cnx;
        *(f32x4*)(G2h + RZ0 + ro) = c0h; *(f32x4*)(G2h + RZ1 + ro) = c1h;
        *(f32x4*)(G2h + NR  + ro) = cnh;
      }
    }
    // x_{t+2} prefetch (issued here, packed in E by the same threads)
    float2 xn;
    if ((tid & ~15) == 256) {
      const int ti = (t + 2 < SEQ) ? t + 2 : SEQ - 1;
      xn = xsrc[(size_t)ti * 16 + (tid - 256)];
    }
    __syncthreads();

    // ================= phase E: state updates =================
    if (tid < 128) {
      if (t >= 0) {  // layer-2 update -> h2_t, output partials
        float r = sigm(G2x[tid] + G2h[tid] + bA);
        float z = sigm(G2x[HID + tid] + G2h[HID + tid] + bB);
        float n = tanh_f(G2x[2 * HID + tid] + bC + r * (G2h[2 * HID + tid] + bD));
        float h = (1.f - z) * n + z * s1f[tid];
        s1f[tid] = h;
        s1h[tid] = (_Float16)h;
        float p = fmaxf(h, 0.f) * wl;
        p += __shfl_xor(p, 1, 64);
        p += __shfl_xor(p, 2, 64);
        p += __shfl_xor(p, 4, 64);
        if ((tid & 7) == 0) pbf[(t & 1) * 16 + (tid >> 3)] = p;
      }
    } else if (tid < 256) {  // layer-1 update -> h1_{t+1}
      const int i = tid - 128;
      float r = sigm(G1x[i] + G1h[i] + bA);
      float z = sigm(G1x[HID + i] + G1h[HID + i] + bB);
      float n = tanh_f(G1x[2 * HID + i] + bC + r * (G1h[2 * HID + i] + bD));
      float h = (1.f - z) * n + z * s0f[i];
      s0f[i] = h;
      s0h[i] = (_Float16)h;
    } else if (tid < 272) {  // pack x_{t+2}
      const int i = tid - 256;
      xh[t & 1][2 * i] = (_Float16)xn.x; xh[t & 1][2 * i + 1] = (_Float16)xn.y;
    } else if (tid == 320 && t >= 1) {  // store out[t-1] from previous partials
      const float4* p4 = (const float4*)(pbf + ((t - 1) & 1) * 16);
      float4 u = p4[0], v = p4[1], w = p4[2], s = p4[3];
      outp[t - 1] = (u.x + u.y + u.z + u.w) + (v.x + v.y + v.z + v.w) +
                    (w.x + w.y + w.z + w.w) + (s.x + s.y + s.z + s.w) + blv;
    }
    __syncthreads();
  }

  if (tid == 0) {
    const float4* p4 = (const float4*)(pbf + ((SEQ - 1) & 1) * 16);
    float4 u = p4[0], v = p4[1], w = p4[2], s = p4[3];
    outp[SEQ - 1] = (u.x + u.y + u.z + u.w) + (v.x + v.y + v.z + v.w) +
                    (w.x + w.y + w.z + w.w) + (s.x + s.y + s.z + s.w) + blv;
  }
}

extern "C" void kernel_launch(void* const* d_in, const int* in_sizes, int n_in,
                              void* d_out, int out_size, void* d_ws, size_t ws_size,
                              hipStream_t stream) {
  const float* x    = (const float*)d_in[0];
  const float* Wih0 = (const float*)d_in[1];
  const float* Whh0 = (const float*)d_in[2];
  const float* bih0 = (const float*)d_in[3];
  const float* bhh0 = (const float*)d_in[4];
  const float* Wih1 = (const float*)d_in[5];
  const float* Whh1 = (const float*)d_in[6];
  const float* bih1 = (const float*)d_in[7];
  const float* bhh1 = (const float*)d_in[8];
  const float* Wlin = (const float*)d_in[9];
  const float* blin = (const float*)d_in[10];
  float* outp = (float*)d_out;

  const int Bn = in_sizes[0] / (SEQ * INSZ);   // 256
  hipLaunchKernelGGL(gru_fused, dim3(Bn), dim3(512), 0, stream,
                     x, Wih0, Whh0, bih0, bhh0,
                     Wih1, Whh1, bih1, bhh1, Wlin, blin, outp);
}

// Round 7
// 1424.323 us; speedup vs baseline: 1.2890x; 1.2890x over previous
//
#include <hip/hip_runtime.h>
#include <hip/hip_bf16.h>

// ---------------------------------------------------------------------------
// Fused 2-layer GRU + ReLU + Linear. One batch element per workgroup (256 WGs).
// Cross-layer pipelined: per step, phase M computes L2 gate pre-acts for time t
// AND L1 gate pre-acts for time t+1; phase E updates both states. 2 barriers.
// Round-7 change: the dot2 is inline asm with "v" register constraints.
// R1-R5 showed the allocator parks the per-thread weight array in AGPRs
// (VGPR_Count 84/128/64 across configs) and pays ~1 v_accvgpr move per dot2
// (VALU busy ~2.7x the dot2 issue floor in every config). Source-level hints
// (launch_bounds, waves_per_eu, LDS pad) all failed to move it. Inline-asm
// "v" constraints are binding: the 156 weight half2s MUST get arch VGPRs
// (~215 total demand fits the 256 cap at 2 waves/SIMD = 512-thread block).
// Work split: quad (4 lanes) owns rows {q, 128+q, 256+q} of both layers,
// k-split x4 across the quad; partials summed by the E-phase reader via LDS.
// ---------------------------------------------------------------------------

typedef _Float16 h2 __attribute__((ext_vector_type(2)));

__device__ __forceinline__ float dot2f(h2 a, h2 b, float c) {
  // VOP3P v_dot2_f32_f16: c += a.x*b.x + a.y*b.y, all operands forced to
  // architectural VGPRs by the "v" constraints.
  asm("v_dot2_f32_f16 %0, %1, %2, %0" : "+v"(c) : "v"(a), "v"(b));
  return c;
}

__device__ __forceinline__ h2 pack2(float x, float y) {
  h2 r; r[0] = (_Float16)x; r[1] = (_Float16)y; return r;
}
__device__ __forceinline__ float sigm(float x) {
  return 1.0f / (1.0f + __expf(-x));
}
__device__ __forceinline__ float tanh_f(float x) {
  x = fminf(fmaxf(x, -15.f), 15.f);
  float e = __expf(2.f * x);
  return (e - 1.f) / (e + 1.f);
}
__device__ __forceinline__ float hsum(float4 v) { return (v.x + v.y) + (v.z + v.w); }

__device__ __forceinline__ void load_pack8(const float* p, h2* w) {
  float4 a = ((const float4*)p)[0], b = ((const float4*)p)[1];
  w[0] = pack2(a.x, a.y); w[1] = pack2(a.z, a.w);
  w[2] = pack2(b.x, b.y); w[3] = pack2(b.z, b.w);
}

#define SEQ 1200
#define HID 128
#define INSZ 32

#define DOT4Q(W, F, ACC)                                                \
  ACC = dot2f((W)[0], __builtin_bit_cast(h2, (F).x), ACC);              \
  ACC = dot2f((W)[1], __builtin_bit_cast(h2, (F).y), ACC);              \
  ACC = dot2f((W)[2], __builtin_bit_cast(h2, (F).z), ACC);              \
  ACC = dot2f((W)[3], __builtin_bit_cast(h2, (F).w), ACC);

#define DOT16Q(W, FA, FB, FC, FD, ACC)                                  \
  DOT4Q(&(W)[0],  FA, ACC) DOT4Q(&(W)[4],  FB, ACC)                     \
  DOT4Q(&(W)[8],  FC, ACC) DOT4Q(&(W)[12], FD, ACC)

__global__ __launch_bounds__(512, 1) void gru_fused(
    const float* __restrict__ x,
    const float* __restrict__ Wih0, const float* __restrict__ Whh0,
    const float* __restrict__ bih0, const float* __restrict__ bhh0,
    const float* __restrict__ Wih1, const float* __restrict__ Whh1,
    const float* __restrict__ bih1, const float* __restrict__ bhh1,
    const float* __restrict__ Wlin, const float* __restrict__ blin,
    float* __restrict__ out)
{
  const int tid = threadIdx.x;
  const int b   = blockIdx.x;
  const int q   = tid >> 2;   // quad id 0..127 -> rows {q, 128+q, 256+q}
  const int ql  = tid & 3;    // k-quarter within the row

  // gate pre-activation partials: [slot(4)][quad(128)][lane(4)] f32
  __shared__ float G1p[4 * 512];   // layer1 (r, z, nx, nh)
  __shared__ float G2p[4 * 512];   // layer2
  __shared__ float  s0f[HID], s1f[HID];        // fp32 master states
  __shared__ float4 s0h4[16], s1h4[16];        // packed fp16 states (128 halfs)
  __shared__ float4 xh[2][4];                  // packed fp16 x row, double buffer
  __shared__ float  pbf[32];                   // output partials, double buffer

  // ---- per-thread weight registers (packed fp16), all compile-time indexed ----
  h2 wi0[3][4];    // W_ih0 rows {q,128+q,256+q}, quarter ql (8 elems each)
  h2 wh0[3][16];   // W_hh0 rows, quarter ql (32 elems each)
  h2 wi1[3][16];   // W_ih1 rows
  h2 wh1[3][16];   // W_hh1 rows
#pragma unroll
  for (int rr = 0; rr < 3; ++rr) {
    const int row = rr * HID + q;
    load_pack8(Wih0 + (size_t)row * INSZ + ql * 8, wi0[rr]);
#pragma unroll
    for (int c = 0; c < 4; ++c) {
      load_pack8(Whh0 + (size_t)row * HID + ql * 32 + c * 8, &wh0[rr][c * 4]);
      load_pack8(Wih1 + (size_t)row * HID + ql * 32 + c * 8, &wi1[rr][c * 4]);
      load_pack8(Whh1 + (size_t)row * HID + ql * 32 + c * 8, &wh1[rr][c * 4]);
    }
  }

  // E-phase per-thread constants
  float bA = 0.f, bB = 0.f, bC = 0.f, bD = 0.f, wl = 0.f;
  if (tid < 128) {                 // L2 updater for row-group tid
    bA = bih1[tid] + bhh1[tid];
    bB = bih1[HID + tid] + bhh1[HID + tid];
    bC = bih1[2 * HID + tid];
    bD = bhh1[2 * HID + tid];
    wl = Wlin[tid];
  } else if (tid < 256) {          // L1 updater
    const int i = tid - 128;
    bA = bih0[i] + bhh0[i];
    bB = bih0[HID + i] + bhh0[HID + i];
    bC = bih0[2 * HID + i];
    bD = bhh0[2 * HID + i];
  }
  const float blv = blin[0];

  // ---- init: zero states, pack x_0 into xh[0] ----
  if (tid < HID) { s0f[tid] = 0.f; s1f[tid] = 0.f; }
  if (tid < 64) { ((float*)s0h4)[tid] = 0.f; ((float*)s1h4)[tid] = 0.f; }
  const float2* xsrc = (const float2*)x + (size_t)b * SEQ * (INSZ / 2);
  if (tid < 16) {
    float2 v = xsrc[tid];
    ((h2*)xh[0])[tid] = pack2(v.x, v.y);
  }
  __syncthreads();

  float* outp = out + (size_t)b * SEQ;

  for (int t = -1; t < SEQ; ++t) {
    // ================= phase M: all matvec partials =================
    {
      const int buf = (t + 1) & 1;
      const float4 xq = xh[buf][ql];
      const float4 sA = s0h4[ql * 4 + 0], sB = s0h4[ql * 4 + 1],
                   sC = s0h4[ql * 4 + 2], sD = s0h4[ql * 4 + 3];
      const float4 tA = s1h4[ql * 4 + 0], tB = s1h4[ql * 4 + 1],
                   tC = s1h4[ql * 4 + 2], tD = s1h4[ql * 4 + 3];
      float a0 = 0.f, a1 = 0.f, a2 = 0.f, a3 = 0.f;
      DOT4Q(wi0[0], xq, a0) DOT16Q(wh0[0], sA, sB, sC, sD, a0)   // L1 r (merged)
      DOT4Q(wi0[1], xq, a1) DOT16Q(wh0[1], sA, sB, sC, sD, a1)   // L1 z (merged)
      DOT4Q(wi0[2], xq, a2)                                      // L1 n, x-part
      DOT16Q(wh0[2], sA, sB, sC, sD, a3)                         // L1 n, h-part
      float c0 = 0.f, c1 = 0.f, c2 = 0.f, c3 = 0.f;
      DOT16Q(wi1[0], sA, sB, sC, sD, c0) DOT16Q(wh1[0], tA, tB, tC, tD, c0)
      DOT16Q(wi1[1], sA, sB, sC, sD, c1) DOT16Q(wh1[1], tA, tB, tC, tD, c1)
      DOT16Q(wi1[2], sA, sB, sC, sD, c2)
      DOT16Q(wh1[2], tA, tB, tC, tD, c3)
      G1p[tid] = a0; G1p[512 + tid] = a1; G1p[1024 + tid] = a2; G1p[1536 + tid] = a3;
      G2p[tid] = c0; G2p[512 + tid] = c1; G2p[1024 + tid] = c2; G2p[1536 + tid] = c3;
    }
    // x_{t+2} prefetch (issued here, packed in E by the same threads)
    float2 xn;
    if ((tid & ~15) == 256) {
      const int ti = (t + 2 < SEQ) ? t + 2 : SEQ - 1;
      xn = xsrc[(size_t)ti * 16 + (tid - 256)];
    }
    __syncthreads();

    // ================= phase E: state updates =================
    if (tid < 128) {
      if (t >= 0) {  // layer-2 update -> h2_t, output partials
        const float4* G4 = (const float4*)G2p;
        float4 r4 = G4[tid], z4 = G4[128 + tid], x4 = G4[256 + tid], h4 = G4[384 + tid];
        float r = sigm(hsum(r4) + bA);
        float z = sigm(hsum(z4) + bB);
        float n = tanh_f(hsum(x4) + bC + r * (hsum(h4) + bD));
        float h = (1.f - z) * n + z * s1f[tid];
        s1f[tid] = h;
        ((_Float16*)s1h4)[tid] = (_Float16)h;
        float p = fmaxf(h, 0.f) * wl;
        p += __shfl_xor(p, 1, 64);
        p += __shfl_xor(p, 2, 64);
        p += __shfl_xor(p, 4, 64);
        if ((tid & 7) == 0) pbf[(t & 1) * 16 + (tid >> 3)] = p;
      }
    } else if (tid < 256) {  // layer-1 update -> h1_{t+1}
      const int i = tid - 128;
      const float4* G4 = (const float4*)G1p;
      float4 r4 = G4[i], z4 = G4[128 + i], x4 = G4[256 + i], h4 = G4[384 + i];
      float r = sigm(hsum(r4) + bA);
      float z = sigm(hsum(z4) + bB);
      float n = tanh_f(hsum(x4) + bC + r * (hsum(h4) + bD));
      float h = (1.f - z) * n + z * s0f[i];
      s0f[i] = h;
      ((_Float16*)s0h4)[i] = (_Float16)h;
    } else if (tid < 272) {  // pack x_{t+2}
      ((h2*)xh[t & 1])[tid - 256] = pack2(xn.x, xn.y);
    } else if (tid == 320 && t >= 1) {  // store out[t-1] from previous partials
      const float4* p4 = (const float4*)(pbf + ((t - 1) & 1) * 16);
      outp[t - 1] = hsum(p4[0]) + hsum(p4[1]) + hsum(p4[2]) + hsum(p4[3]) + blv;
    }
    __syncthreads();
  }

  if (tid == 0) {
    const float4* p4 = (const float4*)(pbf + ((SEQ - 1) & 1) * 16);
    outp[SEQ - 1] = hsum(p4[0]) + hsum(p4[1]) + hsum(p4[2]) + hsum(p4[3]) + blv;
  }
}

extern "C" void kernel_launch(void* const* d_in, const int* in_sizes, int n_in,
                              void* d_out, int out_size, void* d_ws, size_t ws_size,
                              hipStream_t stream) {
  const float* x    = (const float*)d_in[0];
  const float* Wih0 = (const float*)d_in[1];
  const float* Whh0 = (const float*)d_in[2];
  const float* bih0 = (const float*)d_in[3];
  const float* bhh0 = (const float*)d_in[4];
  const float* Wih1 = (const float*)d_in[5];
  const float* Whh1 = (const float*)d_in[6];
  const float* bih1 = (const float*)d_in[7];
  const float* bhh1 = (const float*)d_in[8];
  const float* Wlin = (const float*)d_in[9];
  const float* blin = (const float*)d_in[10];
  float* outp = (float*)d_out;

  const int Bn = in_sizes[0] / (SEQ * INSZ);   // 256
  hipLaunchKernelGGL(gru_fused, dim3(Bn), dim3(512), 0, stream,
                     x, Wih0, Whh0, bih0, bhh0,
                     Wih1, Whh1, bih1, bhh1, Wlin, blin, outp);
}